// Round 9
// baseline (151.491 us; speedup 1.0000x reference)
//
#include <hip/hip_runtime.h>
#include <hip/hip_bf16.h>
#include <hip/hip_fp16.h>

// Triangle attention (starting node), b=1, n=256, d=128, H=4, DH=32.
// Round 8: lane-local PV fragments via key-permuted V^T (no P LDS round
// trip, no shuffles), 37.6KB LDS -> 4 blocks/CU, bf16 frag-ordered bias.

#define NP  256
#define DD  128
#define HSTR 2097152   // 65536*32, per-head block stride (elements)

typedef short bf16x8 __attribute__((ext_vector_type(8)));
typedef float f32x4  __attribute__((ext_vector_type(4)));

__device__ __forceinline__ float bf2f(ushort u) {
    union { unsigned int v; float f; } c; c.v = ((unsigned int)u) << 16; return c.f;
}
__device__ __forceinline__ float asf(unsigned int v) {
    union { unsigned int v; float f; } c; c.v = v; return c.f;
}
__device__ __forceinline__ ushort f2bf(float f) {
    union { float f; unsigned int v; } c; c.f = f;
    unsigned int x = c.v;
    return (ushort)((x + 0x7FFFu + ((x >> 16) & 1u)) >> 16);  // RNE
}
__device__ __forceinline__ unsigned int packbf(float a, float b) {
    __hip_bfloat162 t = __float22bfloat162_rn(make_float2(a, b));  // a -> low
    union { __hip_bfloat162 h; unsigned int u; } c; c.h = t; return c.u;
}
__device__ __forceinline__ f32x4 mfma16(bf16x8 a, bf16x8 b, f32x4 c) {
    return __builtin_amdgcn_mfma_f32_16x16x32_bf16(a, b, c, 0, 0, 0);
}

#define NEGV (-3.4028234663852886e38f)
#define SCALE 0.17677669529663687f

// ---------------- K0: W -> bf16, transposed (N-major, K-contiguous) --------
__global__ __launch_bounds__(256) void k_wconv(
    const float* __restrict__ Wqkv, const float* __restrict__ Wg,
    const float* __restrict__ Wout, ushort* __restrict__ WT,
    ushort* __restrict__ WoT)
{
    int idx = blockIdx.x * 256 + threadIdx.x;   // grid 320 -> 81920
    if (idx < 65536) {
        int n = idx >> 7, k = idx & 127;
        float v = (n < 384) ? Wqkv[(size_t)k * 384 + n]
                            : Wg[(size_t)k * 128 + (n - 384)];
        WT[idx] = f2bf(v);
    } else {
        int i2 = idx - 65536;
        int c = i2 >> 7, e = i2 & 127;
        WoT[i2] = f2bf(Wout[(size_t)e * 128 + c]);
    }
}

// ---------------- K1: LayerNorm -> x bf16, + bias GEMV (bf16, frag-order) --
__global__ __launch_bounds__(256) void k_ln(
    const float* __restrict__ edges, const float* __restrict__ gamma,
    const float* __restrict__ beta,  const float* __restrict__ Wb,
    ushort* __restrict__ Xb, ushort* __restrict__ Bo16)
{
    __shared__ float xs[64][132];
    const int tid = threadIdx.x, w = tid >> 6, lane = tid & 63;
    const int p0 = blockIdx.x * 64;
    const float g0 = gamma[lane], g1 = gamma[lane + 64];
    const float b0 = beta[lane],  b1 = beta[lane + 64];
    for (int pp = 0; pp < 16; ++pp) {
        const int row = w * 16 + pp;
        const float* ep = edges + (size_t)(p0 + row) * DD;
        float e0 = ep[lane], e1 = ep[lane + 64];
        float s = e0 + e1;
        #pragma unroll
        for (int off = 1; off < 64; off <<= 1) s += __shfl_xor(s, off);
        float mu = s * 0.0078125f;
        float d0 = e0 - mu, d1 = e1 - mu;
        float ss = d0 * d0 + d1 * d1;
        #pragma unroll
        for (int off = 1; off < 64; off <<= 1) ss += __shfl_xor(ss, off);
        float rstd = rsqrtf(ss * 0.0078125f + 1e-5f);
        xs[row][lane]      = d0 * rstd * g0 + b0;
        xs[row][lane + 64] = d1 * rstd * g1 + b1;
    }
    __syncthreads();
    #pragma unroll
    for (int pass = 0; pass < 8; ++pass) {
        int idx = pass * 256 + tid;
        int r = idx >> 5, c = (idx & 31) * 4;
        ushort4 o;
        o.x = f2bf(xs[r][c + 0]); o.y = f2bf(xs[r][c + 1]);
        o.z = f2bf(xs[r][c + 2]); o.w = f2bf(xs[r][c + 3]);
        *reinterpret_cast<ushort4*>(&Xb[(size_t)(p0 + r) * DD + c]) = o;
    }
    // bias = x @ Wb, bf16, fragment-ordered: [h][((j*4+lg)*16+fn)*4+r]
    {
        const int r = tid >> 2, hh = tid & 3;
        float acc = 0.f;
        for (int e = 0; e < DD; ++e) acc += xs[r][e] * Wb[e * 4 + hh];
        const int p = p0 + r;
        const int j = p >> 8, k = p & 255;
        const int fn = k >> 4, lgk = (k >> 2) & 3, rr = k & 3;
        Bo16[(size_t)hh * 65536 + (((size_t)j * 4 + lgk) * 16 + fn) * 4 + rr] = f2bf(acc);
    }
}

// ---------------- K2: x @ [Wqkv|Wg] via MFMA; head-blocked outputs ---------
__global__ __launch_bounds__(256) void k_gemm_qkvg(
    const ushort* __restrict__ Xb, const ushort* __restrict__ WT,
    const float* __restrict__ bg,
    ushort* __restrict__ Qo, ushort* __restrict__ Ko,
    ushort* __restrict__ Vo, ushort* __restrict__ Go)
{
    __shared__ __align__(16) ushort As[64][136];
    __shared__ __align__(16) ushort Bs[128][136];
    const int tid = threadIdx.x;
    const int p0 = blockIdx.x * 64;
    #pragma unroll
    for (int it = 0; it < 4; ++it) {
        int idx = it * 256 + tid;
        int r = idx >> 4, c = (idx & 15) * 8;
        *reinterpret_cast<uint4*>(&As[r][c]) =
            *reinterpret_cast<const uint4*>(&Xb[(size_t)(p0 + r) * DD + c]);
    }
    const int w = tid >> 6, lane = tid & 63;
    const int wm = w >> 1, wn = w & 1;
    const int lr = lane & 15, lg = lane >> 4;
    const f32x4 zz = {0.f, 0.f, 0.f, 0.f};

    for (int seg = 0; seg < 4; ++seg) {
        const int n0 = seg * 128;
        __syncthreads();
        #pragma unroll
        for (int it = 0; it < 8; ++it) {
            int idx = it * 256 + tid;
            int r = idx >> 4, c = (idx & 15) * 8;
            *reinterpret_cast<uint4*>(&Bs[r][c]) =
                *reinterpret_cast<const uint4*>(&WT[(size_t)(n0 + r) * DD + c]);
        }
        __syncthreads();
        f32x4 acc[2][4];
        #pragma unroll
        for (int m = 0; m < 2; ++m)
            #pragma unroll
            for (int n = 0; n < 4; ++n) acc[m][n] = zz;
        #pragma unroll
        for (int kk = 0; kk < 4; ++kk) {
            bf16x8 a0 = *reinterpret_cast<const bf16x8*>(&As[wm * 32 + lr][kk * 32 + lg * 8]);
            bf16x8 a1 = *reinterpret_cast<const bf16x8*>(&As[wm * 32 + 16 + lr][kk * 32 + lg * 8]);
            #pragma unroll
            for (int n = 0; n < 4; ++n) {
                bf16x8 b = *reinterpret_cast<const bf16x8*>(&Bs[wn * 64 + n * 16 + lr][kk * 32 + lg * 8]);
                acc[0][n] = mfma16(a0, b, acc[0][n]);
                acc[1][n] = mfma16(a1, b, acc[1][n]);
            }
        }
        #pragma unroll
        for (int n = 0; n < 4; ++n) {
            const int cc = wn * 64 + n * 16 + lr;
            const int hh = cc >> 5, dh = cc & 31;
            const float bgv = (seg == 3) ? bg[cc] : 0.f;
            #pragma unroll
            for (int m = 0; m < 2; ++m) {
                #pragma unroll
                for (int r = 0; r < 4; ++r) {
                    const int p = p0 + wm * 32 + m * 16 + lg * 4 + r;
                    const float v = acc[m][n][r];
                    const size_t off = (size_t)hh * HSTR + (size_t)p * 32 + dh;
                    if (seg == 0)      Qo[off] = f2bf(v * SCALE);
                    else if (seg == 1) Ko[off] = f2bf(v);
                    else if (seg == 2) Vo[off] = f2bf(v);
                    else Go[off] = f2bf(1.0f / (1.0f + __expf(-(v + bgv))));
                }
            }
        }
    }
}

// ---------------- K3: attention; lane-local PV fragments -------------------
// grid 1024 (1 (i,h) per block), 4 blocks/CU. h=(bid&7)>>1 groups heads
// per XCD (bias slice L2-resident). V^T columns are key-permuted so the
// packed P words ARE the PV B-fragment (no LDS round-trip, no shuffles).
__global__ __launch_bounds__(256, 4) void k_attn8(
    const ushort* __restrict__ Qw, const ushort* __restrict__ Kw,
    const ushort* __restrict__ Vw, const ushort* __restrict__ Bo16,
    const int* __restrict__ mask, ushort* __restrict__ OPre)
{
    __shared__ __align__(16) ushort Ks[256][40];   // K rows: 20.0KB
    __shared__ __align__(16) ushort Vt[32][268];   // V^T (key-permuted): 16.75KB
    const int tid = threadIdx.x, w = tid >> 6, lane = tid & 63;
    const int lr = lane & 15, lg = lane >> 4;
    const int bid = blockIdx.x;
    const int h = (bid & 7) >> 1;
    const int i = ((bid >> 3) << 1) | (bid & 1);
    const int ib = i * NP;
    const size_t base = (size_t)h * HSTR + (size_t)ib * 32;   // + k*32 + dh

    // stage K rows (contiguous 16KB)
    #pragma unroll
    for (int it = 0; it < 4; ++it) {
        int idx = it * 256 + tid;
        int r = idx >> 2, c = (idx & 3) * 8;
        *reinterpret_cast<uint4*>(&Ks[r][c]) =
            *reinterpret_cast<const uint4*>(&Kw[base + (size_t)r * 32 + c]);
    }
    // stage V^T with per-32-block key permutation:
    // Vt[d][kpos] = V[sigma(kpos)][d], sigma contiguous over aligned quads.
    #pragma unroll
    for (int it = 0; it < 8; ++it) {
        int idx = it * 256 + tid;
        int d = idx & 31, k4 = (idx >> 5) * 4;
        int kk4 = (k4 & ~31) | (((k4 >> 2) & 1) << 4) | (((k4 >> 3) & 3) << 2);
        ushort4 v;
        v.x = Vw[base + (size_t)(kk4 + 0) * 32 + d];
        v.y = Vw[base + (size_t)(kk4 + 1) * 32 + d];
        v.z = Vw[base + (size_t)(kk4 + 2) * 32 + d];
        v.w = Vw[base + (size_t)(kk4 + 3) * 32 + d];
        *reinterpret_cast<ushort4*>(&Vt[d][k4]) = v;
    }
    __syncthreads();

    const ushort* bias_h = Bo16 + (size_t)h * 65536;
    const f32x4 zz = {0.f, 0.f, 0.f, 0.f};

    for (int jt = 0; jt < 4; ++jt) {
        const int jb = jt * 64 + w * 16;
        const int jq = jb + lr;             // this lane's softmax row
        bf16x8 q = *reinterpret_cast<const bf16x8*>(&Qw[base + (size_t)jq * 32 + lg * 8]);
        // bias: 128 contiguous bytes per lane (fragment-ordered bf16)
        const ushort* bp = bias_h + ((size_t)jq * 4 + lg) * 64;
        f32x4 s[16];
        #pragma unroll
        for (int u = 0; u < 8; ++u) {
            uint4 b4 = *reinterpret_cast<const uint4*>(bp + u * 8);
            f32x4 s0, s1;
            s0[0] = asf(b4.x << 16); s0[1] = asf(b4.x & 0xffff0000u);
            s0[2] = asf(b4.y << 16); s0[3] = asf(b4.y & 0xffff0000u);
            s1[0] = asf(b4.z << 16); s1[1] = asf(b4.z & 0xffff0000u);
            s1[2] = asf(b4.w << 16); s1[3] = asf(b4.w & 0xffff0000u);
            s[2 * u] = s0; s[2 * u + 1] = s1;
        }
        #pragma unroll
        for (int fn = 0; fn < 16; ++fn) {
            bf16x8 a = *reinterpret_cast<const bf16x8*>(&Ks[fn * 16 + lr][lg * 8]);
            s[fn] = mfma16(a, q, s[fn]);    // S^T[k][j]
        }
        // softmax over k for row jq (4-lane group: xor 16, 32)
        float mx = -3.402823466e38f;
        #pragma unroll
        for (int fn = 0; fn < 16; ++fn) {
            float m01 = fmaxf(s[fn][0], s[fn][1]);
            float m23 = fmaxf(s[fn][2], s[fn][3]);
            mx = fmaxf(mx, fmaxf(m01, m23));
        }
        mx = fmaxf(mx, __shfl_xor(mx, 16));
        mx = fmaxf(mx, __shfl_xor(mx, 32));
        float sum = 0.f;
        #pragma unroll
        for (int fn = 0; fn < 16; ++fn) {
            #pragma unroll
            for (int r = 0; r < 4; ++r) {
                float e = __expf(s[fn][r] - mx);
                s[fn][r] = e; sum += e;
            }
        }
        sum += __shfl_xor(sum, 16);
        sum += __shfl_xor(sum, 32);
        const bool masked = (mask[ib + jq] == 0);
        const float iv = masked ? 1.0f : (1.0f / sum);

        // PV: packed P words are the B-fragment directly (key-permuted V^T)
        f32x4 o0 = zz, o1 = zz;
        #pragma unroll
        for (int m = 0; m < 8; ++m) {
            union { unsigned int u[4]; bf16x8 v; } pa;
            pa.u[0] = masked ? 0x3B803B80u : packbf(s[2 * m][0], s[2 * m][1]);
            pa.u[1] = masked ? 0x3B803B80u : packbf(s[2 * m][2], s[2 * m][3]);
            pa.u[2] = masked ? 0x3B803B80u : packbf(s[2 * m + 1][0], s[2 * m + 1][1]);
            pa.u[3] = masked ? 0x3B803B80u : packbf(s[2 * m + 1][2], s[2 * m + 1][3]);
            bf16x8 v0 = *reinterpret_cast<const bf16x8*>(&Vt[lr][m * 32 + lg * 8]);
            bf16x8 v1 = *reinterpret_cast<const bf16x8*>(&Vt[16 + lr][m * 32 + lg * 8]);
            o0 = mfma16(v0, pa.v, o0);
            o1 = mfma16(v1, pa.v, o1);
        }
        // epilogue: lane owns row jq; O[jq][4lg+r] / O[jq][16+4lg+r]
        const size_t off = base + (size_t)jq * 32;
        uint2 u0, u1;
        u0.x = packbf(o0[0] * iv, o0[1] * iv);
        u0.y = packbf(o0[2] * iv, o0[3] * iv);
        u1.x = packbf(o1[0] * iv, o1[1] * iv);
        u1.y = packbf(o1[2] * iv, o1[3] * iv);
        *reinterpret_cast<uint2*>(&OPre[off + 4 * lg])      = u0;
        *reinterpret_cast<uint2*>(&OPre[off + 16 + 4 * lg]) = u1;
    }
}

// ---------------- K4: out = (g .* OPre) @ Wout + bout (gating fused) -------
__device__ __forceinline__ unsigned int gate2(unsigned int o2, unsigned int g2, bool mk) {
    float a0 = bf2f((ushort)(o2 & 0xffffu)), a1 = bf2f((ushort)(o2 >> 16));
    float g0 = mk ? NEGV : bf2f((ushort)(g2 & 0xffffu));
    float g1 = mk ? NEGV : bf2f((ushort)(g2 >> 16));
    return packbf(a0 * g0, a1 * g1);
}

__global__ __launch_bounds__(256) void k_gemm_out(
    const ushort* __restrict__ OPre, const ushort* __restrict__ Gw,
    const int* __restrict__ mask, const ushort* __restrict__ WoT,
    const float* __restrict__ bout, float* __restrict__ out)
{
    __shared__ __align__(16) ushort As[64][136];
    __shared__ __align__(16) ushort Bs[128][136];
    const int tid = threadIdx.x;
    const int p0 = blockIdx.x * 64;
    #pragma unroll
    for (int it = 0; it < 4; ++it) {
        int idx = it * 256 + tid;
        int r = idx >> 4, c = (idx & 15) * 8;
        int hh = c >> 5, dq = c & 31;
        const int p = p0 + r;
        const size_t go = (size_t)hh * HSTR + (size_t)p * 32 + dq;
        uint4 ov = *reinterpret_cast<const uint4*>(&OPre[go]);
        uint4 gv = *reinterpret_cast<const uint4*>(&Gw[go]);
        const bool mk = (mask[p] == 0);
        uint4 rs;
        rs.x = gate2(ov.x, gv.x, mk);
        rs.y = gate2(ov.y, gv.y, mk);
        rs.z = gate2(ov.z, gv.z, mk);
        rs.w = gate2(ov.w, gv.w, mk);
        *reinterpret_cast<uint4*>(&As[r][c]) = rs;
    }
    #pragma unroll
    for (int it = 0; it < 8; ++it) {
        int idx = it * 256 + tid;
        int r = idx >> 4, c = (idx & 15) * 8;
        *reinterpret_cast<uint4*>(&Bs[r][c]) =
            *reinterpret_cast<const uint4*>(&WoT[(size_t)r * DD + c]);
    }
    __syncthreads();
    const int w = tid >> 6, lane = tid & 63;
    const int wm = w >> 1, wn = w & 1;
    const int lr = lane & 15, lg = lane >> 4;
    const f32x4 zz = {0.f, 0.f, 0.f, 0.f};
    f32x4 acc[2][4];
    #pragma unroll
    for (int m = 0; m < 2; ++m)
        #pragma unroll
        for (int n = 0; n < 4; ++n) acc[m][n] = zz;
    #pragma unroll
    for (int kk = 0; kk < 4; ++kk) {
        bf16x8 a0 = *reinterpret_cast<const bf16x8*>(&As[wm * 32 + lr][kk * 32 + lg * 8]);
        bf16x8 a1 = *reinterpret_cast<const bf16x8*>(&As[wm * 32 + 16 + lr][kk * 32 + lg * 8]);
        #pragma unroll
        for (int n = 0; n < 4; ++n) {
            bf16x8 b = *reinterpret_cast<const bf16x8*>(&Bs[wn * 64 + n * 16 + lr][kk * 32 + lg * 8]);
            acc[0][n] = mfma16(a0, b, acc[0][n]);
            acc[1][n] = mfma16(a1, b, acc[1][n]);
        }
    }
    #pragma unroll
    for (int n = 0; n < 4; ++n) {
        const int c = wn * 64 + n * 16 + lr;
        const float bo = bout[c];
        #pragma unroll
        for (int m = 0; m < 2; ++m) {
            #pragma unroll
            for (int r = 0; r < 4; ++r) {
                const int p = p0 + wm * 32 + m * 16 + lg * 4 + r;
                out[(size_t)p * DD + c] = acc[m][n][r] + bo;
            }
        }
    }
}

extern "C" void kernel_launch(void* const* d_in, const int* in_sizes, int n_in,
                              void* d_out, int out_size, void* d_ws, size_t ws_size,
                              hipStream_t stream) {
    const float* edges = (const float*)d_in[0];
    const int*   mask  = (const int*)d_in[1];
    const float* gamma = (const float*)d_in[2];
    const float* beta  = (const float*)d_in[3];
    const float* Wqkv  = (const float*)d_in[4];
    const float* Wb    = (const float*)d_in[5];
    const float* Wg    = (const float*)d_in[6];
    const float* bg    = (const float*)d_in[7];
    const float* Wout  = (const float*)d_in[8];
    const float* bout  = (const float*)d_in[9];
    float* out = (float*)d_out;

    char* ws = (char*)d_ws;
    ushort* Xb  = (ushort*)(ws);                               // 16 MiB
    ushort* Qw  = (ushort*)(ws + 1u * 16777216u);              // head-blocked
    ushort* Kw  = (ushort*)(ws + 2u * 16777216u);
    ushort* Vw  = (ushort*)(ws + 3u * 16777216u);
    ushort* Gw  = (ushort*)(ws + 4u * 16777216u);
    ushort* Bo16 = (ushort*)(ws + 5u * 16777216u);                     // 512 KiB bf16
    ushort* WT  = (ushort*)(ws + 5u * 16777216u + 524288u);            // 128 KiB
    ushort* WoT = (ushort*)(ws + 5u * 16777216u + 524288u + 131072u);  // 32 KiB
    ushort* OPre = Xb;   // Xb dead after k_gemm_qkvg; OPre is head-blocked

    k_wconv<<<dim3(320), dim3(256), 0, stream>>>(Wqkv, Wg, Wout, WT, WoT);
    k_ln<<<dim3(1024), dim3(256), 0, stream>>>(edges, gamma, beta, Wb, Xb, Bo16);
    k_gemm_qkvg<<<dim3(1024), dim3(256), 0, stream>>>(Xb, WT, bg, Qw, Kw, Vw, Gw);
    k_attn8<<<dim3(1024), dim3(256), 0, stream>>>(Qw, Kw, Vw, Bo16, mask, OPre);
    k_gemm_out<<<dim3(1024), dim3(256), 0, stream>>>(OPre, Gw, mask, WoT, bout, out);
}

// Round 10
// 100.520 us; speedup vs baseline: 1.5071x; 1.5071x over previous
//
#include <hip/hip_runtime.h>
#include <hip/hip_bf16.h>
#include <hip/hip_fp16.h>

// Triangle attention (starting node), b=1, n=256, d=128, H=4, DH=32.
// Round 9: round-8 design (lane-local PV fragments via key-permuted V^T,
// no P LDS round-trip) with launch_bounds(256,2) -> 128 VGPRs, no spill.
// (Round 8's launch_bounds(256,4) capped VGPRs at 64 -> scratch spill:
// FETCH 54->206MB, WRITE 44->106MB. Occupancy comes from LDS=37.9KB and
// VGPR=128 anyway: 4 blocks/CU.)

#define NP  256
#define DD  128
#define HSTR 2097152   // 65536*32, per-head block stride (elements)

typedef short bf16x8 __attribute__((ext_vector_type(8)));
typedef float f32x4  __attribute__((ext_vector_type(4)));

__device__ __forceinline__ float bf2f(ushort u) {
    union { unsigned int v; float f; } c; c.v = ((unsigned int)u) << 16; return c.f;
}
__device__ __forceinline__ float asf(unsigned int v) {
    union { unsigned int v; float f; } c; c.v = v; return c.f;
}
__device__ __forceinline__ ushort f2bf(float f) {
    union { float f; unsigned int v; } c; c.f = f;
    unsigned int x = c.v;
    return (ushort)((x + 0x7FFFu + ((x >> 16) & 1u)) >> 16);  // RNE
}
__device__ __forceinline__ unsigned int packbf(float a, float b) {
    __hip_bfloat162 t = __float22bfloat162_rn(make_float2(a, b));  // a -> low
    union { __hip_bfloat162 h; unsigned int u; } c; c.h = t; return c.u;
}
__device__ __forceinline__ f32x4 mfma16(bf16x8 a, bf16x8 b, f32x4 c) {
    return __builtin_amdgcn_mfma_f32_16x16x32_bf16(a, b, c, 0, 0, 0);
}

#define NEGV (-3.4028234663852886e38f)
#define SCALE 0.17677669529663687f

// ---------------- K0: W -> bf16, transposed (N-major, K-contiguous) --------
__global__ __launch_bounds__(256) void k_wconv(
    const float* __restrict__ Wqkv, const float* __restrict__ Wg,
    const float* __restrict__ Wout, ushort* __restrict__ WT,
    ushort* __restrict__ WoT)
{
    int idx = blockIdx.x * 256 + threadIdx.x;   // grid 320 -> 81920
    if (idx < 65536) {
        int n = idx >> 7, k = idx & 127;
        float v = (n < 384) ? Wqkv[(size_t)k * 384 + n]
                            : Wg[(size_t)k * 128 + (n - 384)];
        WT[idx] = f2bf(v);
    } else {
        int i2 = idx - 65536;
        int c = i2 >> 7, e = i2 & 127;
        WoT[i2] = f2bf(Wout[(size_t)e * 128 + c]);
    }
}

// ---------------- K1: LayerNorm -> x bf16, + bias GEMV (bf16, frag-order) --
__global__ __launch_bounds__(256) void k_ln(
    const float* __restrict__ edges, const float* __restrict__ gamma,
    const float* __restrict__ beta,  const float* __restrict__ Wb,
    ushort* __restrict__ Xb, ushort* __restrict__ Bo16)
{
    __shared__ float xs[64][132];
    const int tid = threadIdx.x, w = tid >> 6, lane = tid & 63;
    const int p0 = blockIdx.x * 64;
    const float g0 = gamma[lane], g1 = gamma[lane + 64];
    const float b0 = beta[lane],  b1 = beta[lane + 64];
    for (int pp = 0; pp < 16; ++pp) {
        const int row = w * 16 + pp;
        const float* ep = edges + (size_t)(p0 + row) * DD;
        float e0 = ep[lane], e1 = ep[lane + 64];
        float s = e0 + e1;
        #pragma unroll
        for (int off = 1; off < 64; off <<= 1) s += __shfl_xor(s, off);
        float mu = s * 0.0078125f;
        float d0 = e0 - mu, d1 = e1 - mu;
        float ss = d0 * d0 + d1 * d1;
        #pragma unroll
        for (int off = 1; off < 64; off <<= 1) ss += __shfl_xor(ss, off);
        float rstd = rsqrtf(ss * 0.0078125f + 1e-5f);
        xs[row][lane]      = d0 * rstd * g0 + b0;
        xs[row][lane + 64] = d1 * rstd * g1 + b1;
    }
    __syncthreads();
    #pragma unroll
    for (int pass = 0; pass < 8; ++pass) {
        int idx = pass * 256 + tid;
        int r = idx >> 5, c = (idx & 31) * 4;
        ushort4 o;
        o.x = f2bf(xs[r][c + 0]); o.y = f2bf(xs[r][c + 1]);
        o.z = f2bf(xs[r][c + 2]); o.w = f2bf(xs[r][c + 3]);
        *reinterpret_cast<ushort4*>(&Xb[(size_t)(p0 + r) * DD + c]) = o;
    }
    // bias = x @ Wb, bf16, fragment-ordered: [h][((j*4+lg)*16+fn)*4+r]
    {
        const int r = tid >> 2, hh = tid & 3;
        float acc = 0.f;
        for (int e = 0; e < DD; ++e) acc += xs[r][e] * Wb[e * 4 + hh];
        const int p = p0 + r;
        const int j = p >> 8, k = p & 255;
        const int fn = k >> 4, lgk = (k >> 2) & 3, rr = k & 3;
        Bo16[(size_t)hh * 65536 + (((size_t)j * 4 + lgk) * 16 + fn) * 4 + rr] = f2bf(acc);
    }
}

// ---------------- K2: x @ [Wqkv|Wg] via MFMA; head-blocked outputs ---------
__global__ __launch_bounds__(256) void k_gemm_qkvg(
    const ushort* __restrict__ Xb, const ushort* __restrict__ WT,
    const float* __restrict__ bg,
    ushort* __restrict__ Qo, ushort* __restrict__ Ko,
    ushort* __restrict__ Vo, ushort* __restrict__ Go)
{
    __shared__ __align__(16) ushort As[64][136];
    __shared__ __align__(16) ushort Bs[128][136];
    const int tid = threadIdx.x;
    const int p0 = blockIdx.x * 64;
    #pragma unroll
    for (int it = 0; it < 4; ++it) {
        int idx = it * 256 + tid;
        int r = idx >> 4, c = (idx & 15) * 8;
        *reinterpret_cast<uint4*>(&As[r][c]) =
            *reinterpret_cast<const uint4*>(&Xb[(size_t)(p0 + r) * DD + c]);
    }
    const int w = tid >> 6, lane = tid & 63;
    const int wm = w >> 1, wn = w & 1;
    const int lr = lane & 15, lg = lane >> 4;
    const f32x4 zz = {0.f, 0.f, 0.f, 0.f};

    for (int seg = 0; seg < 4; ++seg) {
        const int n0 = seg * 128;
        __syncthreads();
        #pragma unroll
        for (int it = 0; it < 8; ++it) {
            int idx = it * 256 + tid;
            int r = idx >> 4, c = (idx & 15) * 8;
            *reinterpret_cast<uint4*>(&Bs[r][c]) =
                *reinterpret_cast<const uint4*>(&WT[(size_t)(n0 + r) * DD + c]);
        }
        __syncthreads();
        f32x4 acc[2][4];
        #pragma unroll
        for (int m = 0; m < 2; ++m)
            #pragma unroll
            for (int n = 0; n < 4; ++n) acc[m][n] = zz;
        #pragma unroll
        for (int kk = 0; kk < 4; ++kk) {
            bf16x8 a0 = *reinterpret_cast<const bf16x8*>(&As[wm * 32 + lr][kk * 32 + lg * 8]);
            bf16x8 a1 = *reinterpret_cast<const bf16x8*>(&As[wm * 32 + 16 + lr][kk * 32 + lg * 8]);
            #pragma unroll
            for (int n = 0; n < 4; ++n) {
                bf16x8 b = *reinterpret_cast<const bf16x8*>(&Bs[wn * 64 + n * 16 + lr][kk * 32 + lg * 8]);
                acc[0][n] = mfma16(a0, b, acc[0][n]);
                acc[1][n] = mfma16(a1, b, acc[1][n]);
            }
        }
        #pragma unroll
        for (int n = 0; n < 4; ++n) {
            const int cc = wn * 64 + n * 16 + lr;
            const int hh = cc >> 5, dh = cc & 31;
            const float bgv = (seg == 3) ? bg[cc] : 0.f;
            #pragma unroll
            for (int m = 0; m < 2; ++m) {
                #pragma unroll
                for (int r = 0; r < 4; ++r) {
                    const int p = p0 + wm * 32 + m * 16 + lg * 4 + r;
                    const float v = acc[m][n][r];
                    const size_t off = (size_t)hh * HSTR + (size_t)p * 32 + dh;
                    if (seg == 0)      Qo[off] = f2bf(v * SCALE);
                    else if (seg == 1) Ko[off] = f2bf(v);
                    else if (seg == 2) Vo[off] = f2bf(v);
                    else Go[off] = f2bf(1.0f / (1.0f + __expf(-(v + bgv))));
                }
            }
        }
    }
}

// ---------------- K3: attention; lane-local PV fragments -------------------
// grid 1024 (1 (i,h) per block). h=(bid&7)>>1 groups heads per XCD (bias
// slice L2-resident). V^T columns key-permuted so packed P words ARE the
// PV B-fragment (no LDS round-trip, no shuffles). launch_bounds(256,2)
// -> 128 VGPR (no spill); LDS 37.9KB + VGPR 128 still allow 4 blocks/CU.
__global__ __launch_bounds__(256, 2) void k_attn9(
    const ushort* __restrict__ Qw, const ushort* __restrict__ Kw,
    const ushort* __restrict__ Vw, const ushort* __restrict__ Bo16,
    const int* __restrict__ mask, ushort* __restrict__ OPre)
{
    __shared__ __align__(16) ushort Ks[256][40];   // K rows: 20.0KB
    __shared__ __align__(16) ushort Vt[32][268];   // V^T (key-permuted): 16.75KB
    const int tid = threadIdx.x, w = tid >> 6, lane = tid & 63;
    const int lr = lane & 15, lg = lane >> 4;
    const int bid = blockIdx.x;
    const int h = (bid & 7) >> 1;
    const int i = ((bid >> 3) << 1) | (bid & 1);
    const int ib = i * NP;
    const size_t base = (size_t)h * HSTR + (size_t)ib * 32;   // + k*32 + dh

    // stage K rows (contiguous 16KB)
    #pragma unroll
    for (int it = 0; it < 4; ++it) {
        int idx = it * 256 + tid;
        int r = idx >> 2, c = (idx & 3) * 8;
        *reinterpret_cast<uint4*>(&Ks[r][c]) =
            *reinterpret_cast<const uint4*>(&Kw[base + (size_t)r * 32 + c]);
    }
    // stage V^T with per-32-block key permutation:
    // Vt[d][kpos] = V[sigma(kpos)][d], sigma contiguous over aligned quads.
    #pragma unroll
    for (int it = 0; it < 8; ++it) {
        int idx = it * 256 + tid;
        int d = idx & 31, k4 = (idx >> 5) * 4;
        int kk4 = (k4 & ~31) | (((k4 >> 2) & 1) << 4) | (((k4 >> 3) & 3) << 2);
        ushort4 v;
        v.x = Vw[base + (size_t)(kk4 + 0) * 32 + d];
        v.y = Vw[base + (size_t)(kk4 + 1) * 32 + d];
        v.z = Vw[base + (size_t)(kk4 + 2) * 32 + d];
        v.w = Vw[base + (size_t)(kk4 + 3) * 32 + d];
        *reinterpret_cast<ushort4*>(&Vt[d][k4]) = v;
    }
    __syncthreads();

    const ushort* bias_h = Bo16 + (size_t)h * 65536;
    const f32x4 zz = {0.f, 0.f, 0.f, 0.f};

    for (int jt = 0; jt < 4; ++jt) {
        const int jb = jt * 64 + w * 16;
        const int jq = jb + lr;             // this lane's softmax row
        bf16x8 q = *reinterpret_cast<const bf16x8*>(&Qw[base + (size_t)jq * 32 + lg * 8]);
        // bias: 128 contiguous bytes per lane (fragment-ordered bf16)
        const ushort* bp = bias_h + ((size_t)jq * 4 + lg) * 64;
        f32x4 s[16];
        #pragma unroll
        for (int u = 0; u < 8; ++u) {
            uint4 b4 = *reinterpret_cast<const uint4*>(bp + u * 8);
            f32x4 s0, s1;
            s0[0] = asf(b4.x << 16); s0[1] = asf(b4.x & 0xffff0000u);
            s0[2] = asf(b4.y << 16); s0[3] = asf(b4.y & 0xffff0000u);
            s1[0] = asf(b4.z << 16); s1[1] = asf(b4.z & 0xffff0000u);
            s1[2] = asf(b4.w << 16); s1[3] = asf(b4.w & 0xffff0000u);
            s[2 * u] = s0; s[2 * u + 1] = s1;
        }
        #pragma unroll
        for (int fn = 0; fn < 16; ++fn) {
            bf16x8 a = *reinterpret_cast<const bf16x8*>(&Ks[fn * 16 + lr][lg * 8]);
            s[fn] = mfma16(a, q, s[fn]);    // S^T[k][j]
        }
        // softmax over k for row jq (4-lane group: xor 16, 32)
        float mx = -3.402823466e38f;
        #pragma unroll
        for (int fn = 0; fn < 16; ++fn) {
            float m01 = fmaxf(s[fn][0], s[fn][1]);
            float m23 = fmaxf(s[fn][2], s[fn][3]);
            mx = fmaxf(mx, fmaxf(m01, m23));
        }
        mx = fmaxf(mx, __shfl_xor(mx, 16));
        mx = fmaxf(mx, __shfl_xor(mx, 32));
        float sum = 0.f;
        #pragma unroll
        for (int fn = 0; fn < 16; ++fn) {
            #pragma unroll
            for (int r = 0; r < 4; ++r) {
                float e = __expf(s[fn][r] - mx);
                s[fn][r] = e; sum += e;
            }
        }
        sum += __shfl_xor(sum, 16);
        sum += __shfl_xor(sum, 32);
        const bool masked = (mask[ib + jq] == 0);
        const float iv = masked ? 1.0f : (1.0f / sum);

        // PV: packed P words are the B-fragment directly (key-permuted V^T)
        f32x4 o0 = zz, o1 = zz;
        #pragma unroll
        for (int m = 0; m < 8; ++m) {
            union { unsigned int u[4]; bf16x8 v; } pa;
            pa.u[0] = masked ? 0x3B803B80u : packbf(s[2 * m][0], s[2 * m][1]);
            pa.u[1] = masked ? 0x3B803B80u : packbf(s[2 * m][2], s[2 * m][3]);
            pa.u[2] = masked ? 0x3B803B80u : packbf(s[2 * m + 1][0], s[2 * m + 1][1]);
            pa.u[3] = masked ? 0x3B803B80u : packbf(s[2 * m + 1][2], s[2 * m + 1][3]);
            bf16x8 v0 = *reinterpret_cast<const bf16x8*>(&Vt[lr][m * 32 + lg * 8]);
            bf16x8 v1 = *reinterpret_cast<const bf16x8*>(&Vt[16 + lr][m * 32 + lg * 8]);
            o0 = mfma16(v0, pa.v, o0);
            o1 = mfma16(v1, pa.v, o1);
        }
        // epilogue: lane owns row jq; O[jq][4lg+r] / O[jq][16+4lg+r]
        const size_t off = base + (size_t)jq * 32;
        uint2 u0, u1;
        u0.x = packbf(o0[0] * iv, o0[1] * iv);
        u0.y = packbf(o0[2] * iv, o0[3] * iv);
        u1.x = packbf(o1[0] * iv, o1[1] * iv);
        u1.y = packbf(o1[2] * iv, o1[3] * iv);
        *reinterpret_cast<uint2*>(&OPre[off + 4 * lg])      = u0;
        *reinterpret_cast<uint2*>(&OPre[off + 16 + 4 * lg]) = u1;
    }
}

// ---------------- K4: out = (g .* OPre) @ Wout + bout (gating fused) -------
__device__ __forceinline__ unsigned int gate2(unsigned int o2, unsigned int g2, bool mk) {
    float a0 = bf2f((ushort)(o2 & 0xffffu)), a1 = bf2f((ushort)(o2 >> 16));
    float g0 = mk ? NEGV : bf2f((ushort)(g2 & 0xffffu));
    float g1 = mk ? NEGV : bf2f((ushort)(g2 >> 16));
    return packbf(a0 * g0, a1 * g1);
}

__global__ __launch_bounds__(256) void k_gemm_out(
    const ushort* __restrict__ OPre, const ushort* __restrict__ Gw,
    const int* __restrict__ mask, const ushort* __restrict__ WoT,
    const float* __restrict__ bout, float* __restrict__ out)
{
    __shared__ __align__(16) ushort As[64][136];
    __shared__ __align__(16) ushort Bs[128][136];
    const int tid = threadIdx.x;
    const int p0 = blockIdx.x * 64;
    #pragma unroll
    for (int it = 0; it < 4; ++it) {
        int idx = it * 256 + tid;
        int r = idx >> 4, c = (idx & 15) * 8;
        int hh = c >> 5, dq = c & 31;
        const int p = p0 + r;
        const size_t go = (size_t)hh * HSTR + (size_t)p * 32 + dq;
        uint4 ov = *reinterpret_cast<const uint4*>(&OPre[go]);
        uint4 gv = *reinterpret_cast<const uint4*>(&Gw[go]);
        const bool mk = (mask[p] == 0);
        uint4 rs;
        rs.x = gate2(ov.x, gv.x, mk);
        rs.y = gate2(ov.y, gv.y, mk);
        rs.z = gate2(ov.z, gv.z, mk);
        rs.w = gate2(ov.w, gv.w, mk);
        *reinterpret_cast<uint4*>(&As[r][c]) = rs;
    }
    #pragma unroll
    for (int it = 0; it < 8; ++it) {
        int idx = it * 256 + tid;
        int r = idx >> 4, c = (idx & 15) * 8;
        *reinterpret_cast<uint4*>(&Bs[r][c]) =
            *reinterpret_cast<const uint4*>(&WoT[(size_t)r * DD + c]);
    }
    __syncthreads();
    const int w = tid >> 6, lane = tid & 63;
    const int wm = w >> 1, wn = w & 1;
    const int lr = lane & 15, lg = lane >> 4;
    const f32x4 zz = {0.f, 0.f, 0.f, 0.f};
    f32x4 acc[2][4];
    #pragma unroll
    for (int m = 0; m < 2; ++m)
        #pragma unroll
        for (int n = 0; n < 4; ++n) acc[m][n] = zz;
    #pragma unroll
    for (int kk = 0; kk < 4; ++kk) {
        bf16x8 a0 = *reinterpret_cast<const bf16x8*>(&As[wm * 32 + lr][kk * 32 + lg * 8]);
        bf16x8 a1 = *reinterpret_cast<const bf16x8*>(&As[wm * 32 + 16 + lr][kk * 32 + lg * 8]);
        #pragma unroll
        for (int n = 0; n < 4; ++n) {
            bf16x8 b = *reinterpret_cast<const bf16x8*>(&Bs[wn * 64 + n * 16 + lr][kk * 32 + lg * 8]);
            acc[0][n] = mfma16(a0, b, acc[0][n]);
            acc[1][n] = mfma16(a1, b, acc[1][n]);
        }
    }
    #pragma unroll
    for (int n = 0; n < 4; ++n) {
        const int c = wn * 64 + n * 16 + lr;
        const float bo = bout[c];
        #pragma unroll
        for (int m = 0; m < 2; ++m) {
            #pragma unroll
            for (int r = 0; r < 4; ++r) {
                const int p = p0 + wm * 32 + m * 16 + lg * 4 + r;
                out[(size_t)p * DD + c] = acc[m][n][r] + bo;
            }
        }
    }
}

extern "C" void kernel_launch(void* const* d_in, const int* in_sizes, int n_in,
                              void* d_out, int out_size, void* d_ws, size_t ws_size,
                              hipStream_t stream) {
    const float* edges = (const float*)d_in[0];
    const int*   mask  = (const int*)d_in[1];
    const float* gamma = (const float*)d_in[2];
    const float* beta  = (const float*)d_in[3];
    const float* Wqkv  = (const float*)d_in[4];
    const float* Wb    = (const float*)d_in[5];
    const float* Wg    = (const float*)d_in[6];
    const float* bg    = (const float*)d_in[7];
    const float* Wout  = (const float*)d_in[8];
    const float* bout  = (const float*)d_in[9];
    float* out = (float*)d_out;

    char* ws = (char*)d_ws;
    ushort* Xb  = (ushort*)(ws);                               // 16 MiB
    ushort* Qw  = (ushort*)(ws + 1u * 16777216u);              // head-blocked
    ushort* Kw  = (ushort*)(ws + 2u * 16777216u);
    ushort* Vw  = (ushort*)(ws + 3u * 16777216u);
    ushort* Gw  = (ushort*)(ws + 4u * 16777216u);
    ushort* Bo16 = (ushort*)(ws + 5u * 16777216u);                     // 512 KiB bf16
    ushort* WT  = (ushort*)(ws + 5u * 16777216u + 524288u);            // 128 KiB
    ushort* WoT = (ushort*)(ws + 5u * 16777216u + 524288u + 131072u);  // 32 KiB
    ushort* OPre = Xb;   // Xb dead after k_gemm_qkvg; OPre is head-blocked

    k_wconv<<<dim3(320), dim3(256), 0, stream>>>(Wqkv, Wg, Wout, WT, WoT);
    k_ln<<<dim3(1024), dim3(256), 0, stream>>>(edges, gamma, beta, Wb, Xb, Bo16);
    k_gemm_qkvg<<<dim3(1024), dim3(256), 0, stream>>>(Xb, WT, bg, Qw, Kw, Vw, Gw);
    k_attn9<<<dim3(1024), dim3(256), 0, stream>>>(Qw, Kw, Vw, Bo16, mask, OPre);
    k_gemm_out<<<dim3(1024), dim3(256), 0, stream>>>(OPre, Gw, mask, WoT, bout, out);
}